// Round 2
// baseline (227.835 us; speedup 1.0000x reference)
//
#include <hip/hip_runtime.h>

// RoiAlign (TF crop_and_resize style), fp32, NHWC.
// features: [B,H,W,C] = [2,64,64,256]; rois: [B,N,4] = [2,2000,4]
// out: [B,N,7,7,C]
//
// One wave (64 lanes) per output ROW (b,n,py): loops px=0..6, 4 corner
// float4 loads + lerp + 1 nontemporal float4 store per px.
//
// R3 (re-run; R1 bench was an infra failure, container died pre-run):
// y-band partitioning. Each feature image is 64*64*256*4 = EXACTLY
// 4 MiB = one XCD's L2 capacity; random ROI rows over a working set equal
// to capacity thrash L2 (R2's nt stores helped the write side only; reads
// were still ~784 MB of HBM/L3 traffic -> 216 us @ ~4.6 TB/s effective).
// Now XCD g owns (batch = g>>2, y-quartile = g&3): a wave processes its
// row only if y0>>4 == its quartile. Per-XCD read working set becomes
// 17 rows * 64 KB = 1.09 MiB (+32 KB rois) -> L2-resident. The grid is
// replicated 4x per batch; non-owning copies early-exit after one L2-hit
// 16 B ROI load (ownership is deterministic: all copies compute identical
// y0; exactly one copy owns each row since y0>>4 is in {0..3}). Output
// stores stay NONTEMPORAL so the 200 MB write stream does not evict the
// now-resident band.

#define POOL 7

typedef float vfloat4 __attribute__((ext_vector_type(4)));

__global__ __launch_bounds__(256) void roialign_kernel(
    const float* __restrict__ feat,   // [B,H,W,C]
    const float* __restrict__ rois,   // [B,N,4]
    float* __restrict__ out,          // [B,N,POOL,POOL,C]
    int H, int W, int C4, int N, int blocks_per_batch)
{
    const int lane = threadIdx.x & 63;
    const int wid  = threadIdx.x >> 6;        // wave in block (0..3)

    // XCD-aware decomposition: g = blockIdx%8 lands on XCD g (round-robin
    // heuristic). XCD g serves batch g>>2, y-quartile g&3.
    const int g = blockIdx.x & 7;
    const int b = g >> 2;                     // batch image for this XCD
    const int q = g & 3;                      // y-quartile owned (16 rows)
    const int lblock = blockIdx.x >> 3;       // block index within batch
    if (lblock >= blocks_per_batch) return;

    const int row = lblock * 4 + wid;         // (n,py) row within batch
    const int rows_per_batch = N * POOL;
    if (row >= rows_per_batch) return;

    const int n  = row / POOL;
    const int py = row - n * POOL;

    // ROI load: all lanes same address -> one cacheline, broadcast
    const float* r = rois + ((long long)b * N + n) * 4;
    const float ry1 = r[0], rx1 = r[1], ry2 = r[2], rx2 = r[3];

    // y interpolation (row-uniform)
    const float fy = (float)py * (1.0f / (POOL - 1));
    const float ys = (ry1 + fy * (ry2 - ry1)) * (float)(H - 1);
    const float y0f = fminf(fmaxf(floorf(ys), 0.0f), (float)(H - 1));
    const int   y0  = (int)y0f;

    // y-band ownership check: only the XCD whose quartile contains y0
    // processes this row. Wave-uniform -> clean early exit, no divergence.
    if ((y0 >> 4) != q) return;

    const int   y1i = min(y0 + 1, H - 1);
    const float wy  = ys - y0f;

    const vfloat4* fb = (const vfloat4*)feat + (long long)b * H * W * C4;
    const vfloat4* r0 = fb + (long long)y0  * W * C4 + lane;
    const vfloat4* r1 = fb + (long long)y1i * W * C4 + lane;

    vfloat4* ob = (vfloat4*)out +
                  (((long long)b * N + n) * (POOL * POOL) + (long long)py * POOL) * C4 + lane;

    const float dx = rx2 - rx1;

#pragma unroll
    for (int px = 0; px < POOL; ++px) {
        const float fx  = (float)px * (1.0f / (POOL - 1));
        const float xs  = (rx1 + fx * dx) * (float)(W - 1);
        const float x0f = fminf(fmaxf(floorf(xs), 0.0f), (float)(W - 1));
        const int   x0  = (int)x0f;
        const int   x1i = min(x0 + 1, W - 1);
        const float wx  = xs - x0f;

        const vfloat4 f00 = r0[x0  * C4];
        const vfloat4 f01 = r0[x1i * C4];
        const vfloat4 f10 = r1[x0  * C4];
        const vfloat4 f11 = r1[x1i * C4];

        const vfloat4 top = f00 + (f01 - f00) * wx;
        const vfloat4 bot = f10 + (f11 - f10) * wx;
        const vfloat4 o   = top + (bot - top) * wy;

        __builtin_nontemporal_store(o, ob + px * C4);
    }
}

extern "C" void kernel_launch(void* const* d_in, const int* in_sizes, int n_in,
                              void* d_out, int out_size, void* d_ws, size_t ws_size,
                              hipStream_t stream) {
    const int B = 2, H = 64, W = 64, C = 256;
    const int N = in_sizes[1] / (B * 4);   // rois flat = B*N*4

    const float* feat = (const float*)d_in[0];
    const float* rois = (const float*)d_in[1];
    float* out = (float*)d_out;

    const int rows_per_batch   = N * POOL;                    // 14000
    const int blocks_per_batch = (rows_per_batch + 3) / 4;    // 3500 (4 waves/block)
    const int blocks = blocks_per_batch * 8;                  // 28000 (4 band copies x 2 batches)

    roialign_kernel<<<blocks, 256, 0, stream>>>(feat, rois, out,
                                                H, W, C / 4, N, blocks_per_batch);
}